// Round 3
// baseline (413.321 us; speedup 1.0000x reference)
//
#include <hip/hip_runtime.h>
#include <hip/hip_bf16.h>

#define D 128
#define NG 128
#define PROWS 128

typedef __attribute__((ext_vector_type(8))) short bf16x8;
typedef __attribute__((ext_vector_type(4))) float f32x4;

__device__ inline unsigned short f2bf(float f) {
  union { float f; unsigned u; } c; c.f = f;
  unsigned u = c.u;
  return (unsigned short)((u + 0x7FFFu + ((u >> 16) & 1u)) >> 16);  // RNE
}
__device__ inline float bf2f(unsigned short b) {
  union { unsigned u; float f; } c; c.u = ((unsigned)b) << 16;
  return c.f;
}

// Transpose + bf16-convert weights: Wt[l][n][k] = bf16(W[l][k][n]).
// Also zeroes deg[], g[], counts[] (folded to save launches).
__global__ void prep_w(const float* __restrict__ W1, const float* __restrict__ W2,
                       unsigned short* __restrict__ Wt1, unsigned short* __restrict__ Wt2,
                       int* __restrict__ deg, int N,
                       float* __restrict__ g, int* __restrict__ counts) {
  int t = blockIdx.x * 256 + threadIdx.x;
  if (t < N) deg[t] = 0;
  if (t < NG * D) g[t] = 0.f;
  if (t < NG) counts[t] = 0;
  if (t >= 3 * 128 * 128) return;
  int l = t >> 14, k = (t >> 7) & 127, n = t & 127;
  int o = (l << 14) + (n << 7) + k;
  Wt1[o] = f2bf(W1[t]);
  Wt2[o] = f2bf(W2[t]);
}

// ---------------- CSR build ------------------------------------------------

__global__ void hist_deg(const int* __restrict__ dst, int* __restrict__ deg, int E) {
  int e = blockIdx.x * 256 + threadIdx.x;
  if (e < E) atomicAdd(deg + dst[e], 1);
}

__global__ __launch_bounds__(256) void scan1(const int* __restrict__ deg,
    int* __restrict__ rowptr, int* __restrict__ bsum, int n) {
  __shared__ int sh[256];
  int tid = threadIdx.x;
  int idx = blockIdx.x * 1024 + tid * 4;
  int v[4], tsum = 0;
#pragma unroll
  for (int j = 0; j < 4; ++j) { v[j] = (idx + j < n) ? deg[idx + j] : 0; tsum += v[j]; }
  sh[tid] = tsum;
  __syncthreads();
  for (int off = 1; off < 256; off <<= 1) {
    int x = (tid >= off) ? sh[tid - off] : 0;
    __syncthreads();
    sh[tid] += x;
    __syncthreads();
  }
  if (tid == 255) bsum[blockIdx.x] = sh[255];
  int run = sh[tid] - tsum;
#pragma unroll
  for (int j = 0; j < 4; ++j) { if (idx + j < n) rowptr[idx + j] = run; run += v[j]; }
}

// single 128-thread block scan of per-block sums (nb <= 128)
__global__ __launch_bounds__(128) void scan2(int* __restrict__ bsum, int nb) {
  __shared__ int sh[128];
  int tid = threadIdx.x;
  int v = (tid < nb) ? bsum[tid] : 0;
  sh[tid] = v;
  __syncthreads();
  for (int off = 1; off < 128; off <<= 1) {
    int x = (tid >= off) ? sh[tid - off] : 0;
    __syncthreads();
    sh[tid] += x;
    __syncthreads();
  }
  if (tid < nb) bsum[tid] = sh[tid] - v;
}

__global__ void scan3(int* __restrict__ rowptr, int* __restrict__ pos,
                      const int* __restrict__ bsum, int n, int E) {
  int t = blockIdx.x * 256 + threadIdx.x;
  if (t < n) {
    int v = rowptr[t] + bsum[t >> 10];
    rowptr[t] = v;
    pos[t] = v;
  }
  if (t == 0) rowptr[n] = E;
}

__global__ void edge_scatter(const int* __restrict__ src, const int* __restrict__ dst,
                             int* __restrict__ pos, int* __restrict__ csr_src, int E) {
  int e = blockIdx.x * 256 + threadIdx.x;
  if (e >= E) return;
  int idx = atomicAdd(pos + dst[e], 1);
  csr_src[idx] = src[e];
}

// ---------------- gather aggregation: agg[i] = z[i] + sum neighbors --------
// 8 lanes per node (32B/lane bf16). Per edge each lane issues 2 (bf16) or 4
// (f32) independent 16B loads; 4-edge (bf16) / 2-edge (f32) batches keep 8
// loads in flight per lane. Standalone kernel -> full grid (12 blocks/CU)
// so wave-level parallelism also feeds the memory system (the R2 fused
// version proved 3 blocks/CU starves it).

template<bool IN_BF16>
__global__ __launch_bounds__(256) void gather_agg(const void* __restrict__ zin,
    const int* __restrict__ rowptr, const int* __restrict__ csr_src,
    unsigned short* __restrict__ agg, int N) {
  int t = blockIdx.x * 256 + threadIdx.x;
  int node = t >> 3;
  if (node >= N) return;
  int c = (t & 7) * 16;    // 16 elements per lane: 32B bf16 / 64B f32
  const float* zf = (const float*)zin;
  const unsigned short* zb = (const unsigned short*)zin;

  float acc[16];

  // self term
  if constexpr (IN_BF16) {
    const unsigned short* p = zb + (size_t)node * D + c;
    bf16x8 v0 = *(const bf16x8*)(p);
    bf16x8 v1 = *(const bf16x8*)(p + 8);
#pragma unroll
    for (int j = 0; j < 8; ++j) {
      acc[j]     = bf2f((unsigned short)v0[j]);
      acc[j + 8] = bf2f((unsigned short)v1[j]);
    }
  } else {
    const float* p = zf + (size_t)node * D + c;
    float4 v0 = *(const float4*)(p);
    float4 v1 = *(const float4*)(p + 4);
    float4 v2 = *(const float4*)(p + 8);
    float4 v3 = *(const float4*)(p + 12);
    acc[0]  = v0.x; acc[1]  = v0.y; acc[2]  = v0.z; acc[3]  = v0.w;
    acc[4]  = v1.x; acc[5]  = v1.y; acc[6]  = v1.z; acc[7]  = v1.w;
    acc[8]  = v2.x; acc[9]  = v2.y; acc[10] = v2.z; acc[11] = v2.w;
    acc[12] = v3.x; acc[13] = v3.y; acc[14] = v3.z; acc[15] = v3.w;
  }

  int e  = rowptr[node];
  int e1 = rowptr[node + 1];

  if constexpr (IN_BF16) {
    // 4-edge batches: 8 independent 16B loads in flight
    for (; e + 4 <= e1; e += 4) {
      int s0 = csr_src[e + 0];
      int s1 = csr_src[e + 1];
      int s2 = csr_src[e + 2];
      int s3 = csr_src[e + 3];
      const unsigned short* p0 = zb + (size_t)s0 * D + c;
      const unsigned short* p1 = zb + (size_t)s1 * D + c;
      const unsigned short* p2 = zb + (size_t)s2 * D + c;
      const unsigned short* p3 = zb + (size_t)s3 * D + c;
      bf16x8 a0 = *(const bf16x8*)(p0), a1 = *(const bf16x8*)(p0 + 8);
      bf16x8 b0 = *(const bf16x8*)(p1), b1 = *(const bf16x8*)(p1 + 8);
      bf16x8 c0 = *(const bf16x8*)(p2), c1 = *(const bf16x8*)(p2 + 8);
      bf16x8 d0 = *(const bf16x8*)(p3), d1 = *(const bf16x8*)(p3 + 8);
#pragma unroll
      for (int j = 0; j < 8; ++j) {
        acc[j]     += (bf2f((unsigned short)a0[j]) + bf2f((unsigned short)b0[j]))
                    + (bf2f((unsigned short)c0[j]) + bf2f((unsigned short)d0[j]));
        acc[j + 8] += (bf2f((unsigned short)a1[j]) + bf2f((unsigned short)b1[j]))
                    + (bf2f((unsigned short)c1[j]) + bf2f((unsigned short)d1[j]));
      }
    }
    if (e + 2 <= e1) {
      int s0 = csr_src[e + 0];
      int s1 = csr_src[e + 1];
      const unsigned short* p0 = zb + (size_t)s0 * D + c;
      const unsigned short* p1 = zb + (size_t)s1 * D + c;
      bf16x8 a0 = *(const bf16x8*)(p0), a1 = *(const bf16x8*)(p0 + 8);
      bf16x8 b0 = *(const bf16x8*)(p1), b1 = *(const bf16x8*)(p1 + 8);
#pragma unroll
      for (int j = 0; j < 8; ++j) {
        acc[j]     += bf2f((unsigned short)a0[j]) + bf2f((unsigned short)b0[j]);
        acc[j + 8] += bf2f((unsigned short)a1[j]) + bf2f((unsigned short)b1[j]);
      }
      e += 2;
    }
    if (e < e1) {
      int s0 = csr_src[e];
      const unsigned short* p0 = zb + (size_t)s0 * D + c;
      bf16x8 a0 = *(const bf16x8*)(p0), a1 = *(const bf16x8*)(p0 + 8);
#pragma unroll
      for (int j = 0; j < 8; ++j) {
        acc[j]     += bf2f((unsigned short)a0[j]);
        acc[j + 8] += bf2f((unsigned short)a1[j]);
      }
    }
  } else {
    // f32: 2-edge batches, 8 independent 16B loads in flight
    for (; e + 2 <= e1; e += 2) {
      int s0 = csr_src[e + 0];
      int s1 = csr_src[e + 1];
      const float* p0 = zf + (size_t)s0 * D + c;
      const float* p1 = zf + (size_t)s1 * D + c;
      float4 u0 = *(const float4*)(p0);
      float4 u1 = *(const float4*)(p0 + 4);
      float4 u2 = *(const float4*)(p0 + 8);
      float4 u3 = *(const float4*)(p0 + 12);
      float4 w0 = *(const float4*)(p1);
      float4 w1 = *(const float4*)(p1 + 4);
      float4 w2 = *(const float4*)(p1 + 8);
      float4 w3 = *(const float4*)(p1 + 12);
      acc[0]  += u0.x + w0.x; acc[1]  += u0.y + w0.y;
      acc[2]  += u0.z + w0.z; acc[3]  += u0.w + w0.w;
      acc[4]  += u1.x + w1.x; acc[5]  += u1.y + w1.y;
      acc[6]  += u1.z + w1.z; acc[7]  += u1.w + w1.w;
      acc[8]  += u2.x + w2.x; acc[9]  += u2.y + w2.y;
      acc[10] += u2.z + w2.z; acc[11] += u2.w + w2.w;
      acc[12] += u3.x + w3.x; acc[13] += u3.y + w3.y;
      acc[14] += u3.z + w3.z; acc[15] += u3.w + w3.w;
    }
    if (e < e1) {
      int s0 = csr_src[e];
      const float* p0 = zf + (size_t)s0 * D + c;
      float4 u0 = *(const float4*)(p0);
      float4 u1 = *(const float4*)(p0 + 4);
      float4 u2 = *(const float4*)(p0 + 8);
      float4 u3 = *(const float4*)(p0 + 12);
      acc[0]  += u0.x; acc[1]  += u0.y; acc[2]  += u0.z; acc[3]  += u0.w;
      acc[4]  += u1.x; acc[5]  += u1.y; acc[6]  += u1.z; acc[7]  += u1.w;
      acc[8]  += u2.x; acc[9]  += u2.y; acc[10] += u2.z; acc[11] += u2.w;
      acc[12] += u3.x; acc[13] += u3.y; acc[14] += u3.z; acc[15] += u3.w;
    }
  }

  bf16x8 o0, o1;
#pragma unroll
  for (int j = 0; j < 8; ++j) {
    o0[j] = (short)f2bf(acc[j]);
    o1[j] = (short)f2bf(acc[j + 8]);
  }
  unsigned short* q = agg + (size_t)node * D + c;
  *(bf16x8*)(q)     = o0;
  *(bf16x8*)(q + 8) = o1;
}

// ---------------- fused per-layer MLP: z = ReLU(ReLU(A@W1+b1)@W2+b2) -------
// 16 rows per warp (64/block, grid=1563 -> ~6 blocks/CU; the 45us R0 gemm at
// 3 blocks/CU was latency-bound, not BW-bound). Non-LAST z is staged through
// LDS and written as bf16x8 (1KB contiguous per wave-instruction) instead of
// scattered 2B stores.

template<bool LAST>
__global__ __launch_bounds__(256) void gemm_fused(const unsigned short* __restrict__ A,
    const unsigned short* __restrict__ Wt1, const float* __restrict__ b1v,
    const unsigned short* __restrict__ Wt2, const float* __restrict__ b2v,
    unsigned short* __restrict__ Zb, float* __restrict__ Zf, int M) {
  __shared__ unsigned short hs[4][16][136];
  int lane = threadIdx.x & 63;
  int wid  = threadIdx.x >> 6;
  int rb = blockIdx.x * 64 + wid * 16;
  int c16 = lane & 15;
  int kq  = lane >> 4;
  int koff = kq * 8;

  bf16x8 a[4];
  {
    int row = rb + c16;
    if (row >= M) row = M - 1;
    const unsigned short* p = A + (size_t)row * D + koff;
#pragma unroll
    for (int kk = 0; kk < 4; ++kk) a[kk] = *(const bf16x8*)(p + kk * 32);
  }

  // GEMM1 -> LDS (warp-private 16-row tile)
#pragma unroll
  for (int fc = 0; fc < 8; ++fc) {
    f32x4 acc = {0.f, 0.f, 0.f, 0.f};
    int col = fc * 16 + c16;
#pragma unroll
    for (int kk = 0; kk < 4; ++kk) {
      bf16x8 b = *(const bf16x8*)(Wt1 + (size_t)col * D + kk * 32 + koff);
      acc = __builtin_amdgcn_mfma_f32_16x16x32_bf16(a[kk], b, acc, 0, 0, 0);
    }
    float bv = b1v[col];
#pragma unroll
    for (int r = 0; r < 4; ++r)
      hs[wid][kq * 4 + r][col] = f2bf(fmaxf(acc[r] + bv, 0.f));
  }
  __syncthreads();

  bf16x8 a2[4];
#pragma unroll
  for (int kk = 0; kk < 4; ++kk)
    a2[kk] = *(const bf16x8*)&hs[wid][c16][kk * 32 + koff];
  if constexpr (!LAST) __syncthreads();   // drain a2 reads before z-tile overwrite

  // GEMM2
#pragma unroll
  for (int fc = 0; fc < 8; ++fc) {
    f32x4 acc = {0.f, 0.f, 0.f, 0.f};
    int col = fc * 16 + c16;
#pragma unroll
    for (int kk = 0; kk < 4; ++kk) {
      bf16x8 b = *(const bf16x8*)(Wt2 + (size_t)col * D + kk * 32 + koff);
      acc = __builtin_amdgcn_mfma_f32_16x16x32_bf16(a2[kk], b, acc, 0, 0, 0);
    }
    float bv = b2v[col];
    if constexpr (LAST) {
#pragma unroll
      for (int r = 0; r < 4; ++r) {
        int row = rb + kq * 4 + r;
        if (row < M) Zf[(size_t)row * D + col] = fmaxf(acc[r] + bv, 0.f);
      }
    } else {
#pragma unroll
      for (int r = 0; r < 4; ++r)
        hs[wid][kq * 4 + r][col] = f2bf(fmaxf(acc[r] + bv, 0.f));
    }
  }

  if constexpr (!LAST) {
    __syncthreads();
    // wide coalesced z stores: per i, the wave writes 4 full rows (1KB)
#pragma unroll
    for (int i = 0; i < 4; ++i) {
      int rl = i * 4 + kq;
      int ce = c16 * 8;
      bf16x8 v = *(const bf16x8*)&hs[wid][rl][ce];
      int row = rb + rl;
      if (row < M)
        *(bf16x8*)(Zb + (size_t)row * D + ce) = v;
    }
  }
}

// ---------------- pooling: sorted batch -> chunked segmented mean ----------

__global__ __launch_bounds__(128) void pool_accum(const float* __restrict__ z,
    const int* __restrict__ batch, float* __restrict__ g, int* __restrict__ counts, int N) {
  int col = threadIdx.x;
  int r0 = blockIdx.x * PROWS;
  if (r0 >= N) return;
  int r1 = min(r0 + PROWS, N);
  float acc = 0.f;
  int cur = batch[r0];
  int segstart = r0;
  for (int i = r0; i < r1; ++i) {
    int b = batch[i];
    if (b != cur) {
      atomicAdd(g + (size_t)cur * D + col, acc);
      if (col == 0) atomicAdd(counts + cur, i - segstart);
      acc = 0.f; cur = b; segstart = i;
    }
    acc += z[(size_t)i * D + col];
  }
  atomicAdd(g + (size_t)cur * D + col, acc);
  if (col == 0) atomicAdd(counts + cur, r1 - segstart);
}

__global__ void pool_div(float* __restrict__ g, const int* __restrict__ counts) {
  int t = blockIdx.x * 256 + threadIdx.x;
  if (t >= NG * D) return;
  g[t] = g[t] / fmaxf((float)counts[t >> 7], 1.f);
}

extern "C" void kernel_launch(void* const* d_in, const int* in_sizes, int n_in,
                              void* d_out, int out_size, void* d_ws, size_t ws_size,
                              hipStream_t stream) {
  const float* x     = (const float*)d_in[0];
  const int*   ei    = (const int*)d_in[1];
  const int*   batch = (const int*)d_in[2];
  const float* W1    = (const float*)d_in[3];
  const float* b1    = (const float*)d_in[4];
  const float* W2    = (const float*)d_in[5];
  const float* b2    = (const float*)d_in[6];

  const int N = in_sizes[0] / D;       // 100000
  const int E = in_sizes[1] / 2;       // 640000
  const int* src = ei;
  const int* dst = ei + E;

  float* zout = (float*)d_out;
  float* g    = zout + (size_t)N * D;

  // workspace layout
  char* w = (char*)d_ws;
  unsigned short* agg     = (unsigned short*)w;    w += (size_t)N * D * 2;
  unsigned short* zb      = (unsigned short*)w;    w += (size_t)N * D * 2;
  unsigned short* Wt1     = (unsigned short*)w;    w += 3 * 16384 * 2;
  unsigned short* Wt2     = (unsigned short*)w;    w += 3 * 16384 * 2;
  int*            counts  = (int*)w;               w += NG * 4;
  int*            deg     = (int*)w;               w += (size_t)N * 4;
  int*            rowptr  = (int*)w;               w += (size_t)(N + 4) * 4;
  int*            pos     = (int*)w;               w += (size_t)N * 4;
  int*            bsum    = (int*)w;               w += 128 * 4;
  int*            csr_src = (int*)w;               w += (size_t)E * 4;

  const int nb = (N + 1023) / 1024;   // 98 <= 128

  // weight prep + deg/g/counts zero (folded)
  int prep_threads = (3 * 128 * 128 > N) ? 3 * 128 * 128 : N;
  prep_w<<<(prep_threads + 255) / 256, 256, 0, stream>>>(W1, W2, Wt1, Wt2, deg, N, g, counts);

  // CSR build
  hist_deg<<<(E + 255) / 256, 256, 0, stream>>>(dst, deg, E);
  scan1<<<nb, 256, 0, stream>>>(deg, rowptr, bsum, N);
  scan2<<<1, 128, 0, stream>>>(bsum, nb);
  scan3<<<(N + 255) / 256, 256, 0, stream>>>(rowptr, pos, bsum, N, E);
  edge_scatter<<<(E + 255) / 256, 256, 0, stream>>>(src, dst, pos, csr_src, E);

  const int gather_blocks = (int)(((size_t)N * 8 + 255) / 256);   // 3125
  const int gemm_blocks   = (N + 63) / 64;                        // 1563

  // layer 0 (input f32 x)
  gather_agg<false><<<gather_blocks, 256, 0, stream>>>(x, rowptr, csr_src, agg, N);
  gemm_fused<false><<<gemm_blocks, 256, 0, stream>>>(agg, Wt1, b1, Wt2, b2, zb, zout, N);
  // layer 1
  gather_agg<true><<<gather_blocks, 256, 0, stream>>>(zb, rowptr, csr_src, agg, N);
  gemm_fused<false><<<gemm_blocks, 256, 0, stream>>>(agg, Wt1 + 16384, b1 + 128,
                                                     Wt2 + 16384, b2 + 128, zb, zout, N);
  // layer 2 (writes f32 zout)
  gather_agg<true><<<gather_blocks, 256, 0, stream>>>(zb, rowptr, csr_src, agg, N);
  gemm_fused<true><<<gemm_blocks, 256, 0, stream>>>(agg, Wt1 + 32768, b1 + 256,
                                                    Wt2 + 32768, b2 + 256, zb, zout, N);

  pool_accum<<<(N + PROWS - 1) / PROWS, 128, 0, stream>>>(zout, batch, g, counts, N);
  pool_div<<<(NG * D + 255) / 256, 256, 0, stream>>>(g, counts);
}

// Round 4
// 336.032 us; speedup vs baseline: 1.2300x; 1.2300x over previous
//
#include <hip/hip_runtime.h>
#include <hip/hip_bf16.h>

#define D 128
#define NG 128

typedef __attribute__((ext_vector_type(8))) short bf16x8;
typedef __attribute__((ext_vector_type(4))) float f32x4;

__device__ inline unsigned short f2bf(float f) {
  union { float f; unsigned u; } c; c.f = f;
  unsigned u = c.u;
  return (unsigned short)((u + 0x7FFFu + ((u >> 16) & 1u)) >> 16);  // RNE
}
__device__ inline float bf2f(unsigned short b) {
  union { unsigned u; float f; } c; c.u = ((unsigned)b) << 16;
  return c.f;
}

// Transpose + bf16-convert weights: Wt[l][n][k] = bf16(W[l][k][n]).
// Also zeroes deg[] and g[] (folded to save launches).
__global__ void prep_w(const float* __restrict__ W1, const float* __restrict__ W2,
                       unsigned short* __restrict__ Wt1, unsigned short* __restrict__ Wt2,
                       int* __restrict__ deg, int N, float* __restrict__ g) {
  int t = blockIdx.x * 256 + threadIdx.x;
  if (t < N) deg[t] = 0;
  if (t < NG * D) g[t] = 0.f;
  if (t >= 3 * 128 * 128) return;
  int l = t >> 14, k = (t >> 7) & 127, n = t & 127;
  int o = (l << 14) + (n << 7) + k;
  Wt1[o] = f2bf(W1[t]);
  Wt2[o] = f2bf(W2[t]);
}

// ---------------- CSR build ------------------------------------------------

__global__ void hist_deg(const int* __restrict__ dst, int* __restrict__ deg, int E) {
  int e = blockIdx.x * 256 + threadIdx.x;
  if (e < E) atomicAdd(deg + dst[e], 1);
}

__global__ __launch_bounds__(256) void scan1(const int* __restrict__ deg,
    int* __restrict__ rowptr, int* __restrict__ bsum, int n) {
  __shared__ int sh[256];
  int tid = threadIdx.x;
  int idx = blockIdx.x * 1024 + tid * 4;
  int v[4], tsum = 0;
#pragma unroll
  for (int j = 0; j < 4; ++j) { v[j] = (idx + j < n) ? deg[idx + j] : 0; tsum += v[j]; }
  sh[tid] = tsum;
  __syncthreads();
  for (int off = 1; off < 256; off <<= 1) {
    int x = (tid >= off) ? sh[tid - off] : 0;
    __syncthreads();
    sh[tid] += x;
    __syncthreads();
  }
  if (tid == 255) bsum[blockIdx.x] = sh[255];
  int run = sh[tid] - tsum;
#pragma unroll
  for (int j = 0; j < 4; ++j) { if (idx + j < n) rowptr[idx + j] = run; run += v[j]; }
}

// single 128-thread block scan of per-block sums (nb <= 128)
__global__ __launch_bounds__(128) void scan2(int* __restrict__ bsum, int nb) {
  __shared__ int sh[128];
  int tid = threadIdx.x;
  int v = (tid < nb) ? bsum[tid] : 0;
  sh[tid] = v;
  __syncthreads();
  for (int off = 1; off < 128; off <<= 1) {
    int x = (tid >= off) ? sh[tid - off] : 0;
    __syncthreads();
    sh[tid] += x;
    __syncthreads();
  }
  if (tid < nb) bsum[tid] = sh[tid] - v;
}

__global__ void scan3(int* __restrict__ rowptr, int* __restrict__ pos,
                      const int* __restrict__ bsum, int n, int E) {
  int t = blockIdx.x * 256 + threadIdx.x;
  if (t < n) {
    int v = rowptr[t] + bsum[t >> 10];
    rowptr[t] = v;
    pos[t] = v;
  }
  if (t == 0) rowptr[n] = E;
}

__global__ void edge_scatter(const int* __restrict__ src, const int* __restrict__ dst,
                             int* __restrict__ pos, int* __restrict__ csr_src, int E) {
  int e = blockIdx.x * 256 + threadIdx.x;
  if (e >= E) return;
  int idx = atomicAdd(pos + dst[e], 1);
  csr_src[idx] = src[e];
}

// ---------------- gather aggregation: agg[i] = z[i] + sum neighbors --------
// 8 lanes per node; per lane 2 (bf16) / 4 (f32) independent 16B loads per
// edge, batched so 8 loads are in flight. Full grid for wave-parallelism.

template<bool IN_BF16>
__global__ __launch_bounds__(256) void gather_agg(const void* __restrict__ zin,
    const int* __restrict__ rowptr, const int* __restrict__ csr_src,
    unsigned short* __restrict__ agg, int N) {
  int t = blockIdx.x * 256 + threadIdx.x;
  int node = t >> 3;
  if (node >= N) return;
  int c = (t & 7) * 16;    // 16 elements per lane: 32B bf16 / 64B f32
  const float* zf = (const float*)zin;
  const unsigned short* zb = (const unsigned short*)zin;

  float acc[16];

  // self term
  if constexpr (IN_BF16) {
    const unsigned short* p = zb + (size_t)node * D + c;
    bf16x8 v0 = *(const bf16x8*)(p);
    bf16x8 v1 = *(const bf16x8*)(p + 8);
#pragma unroll
    for (int j = 0; j < 8; ++j) {
      acc[j]     = bf2f((unsigned short)v0[j]);
      acc[j + 8] = bf2f((unsigned short)v1[j]);
    }
  } else {
    const float* p = zf + (size_t)node * D + c;
    float4 v0 = *(const float4*)(p);
    float4 v1 = *(const float4*)(p + 4);
    float4 v2 = *(const float4*)(p + 8);
    float4 v3 = *(const float4*)(p + 12);
    acc[0]  = v0.x; acc[1]  = v0.y; acc[2]  = v0.z; acc[3]  = v0.w;
    acc[4]  = v1.x; acc[5]  = v1.y; acc[6]  = v1.z; acc[7]  = v1.w;
    acc[8]  = v2.x; acc[9]  = v2.y; acc[10] = v2.z; acc[11] = v2.w;
    acc[12] = v3.x; acc[13] = v3.y; acc[14] = v3.z; acc[15] = v3.w;
  }

  int e  = rowptr[node];
  int e1 = rowptr[node + 1];

  if constexpr (IN_BF16) {
    for (; e + 4 <= e1; e += 4) {
      int s0 = csr_src[e + 0];
      int s1 = csr_src[e + 1];
      int s2 = csr_src[e + 2];
      int s3 = csr_src[e + 3];
      const unsigned short* p0 = zb + (size_t)s0 * D + c;
      const unsigned short* p1 = zb + (size_t)s1 * D + c;
      const unsigned short* p2 = zb + (size_t)s2 * D + c;
      const unsigned short* p3 = zb + (size_t)s3 * D + c;
      bf16x8 a0 = *(const bf16x8*)(p0), a1 = *(const bf16x8*)(p0 + 8);
      bf16x8 b0 = *(const bf16x8*)(p1), b1 = *(const bf16x8*)(p1 + 8);
      bf16x8 c0 = *(const bf16x8*)(p2), c1 = *(const bf16x8*)(p2 + 8);
      bf16x8 d0 = *(const bf16x8*)(p3), d1 = *(const bf16x8*)(p3 + 8);
#pragma unroll
      for (int j = 0; j < 8; ++j) {
        acc[j]     += (bf2f((unsigned short)a0[j]) + bf2f((unsigned short)b0[j]))
                    + (bf2f((unsigned short)c0[j]) + bf2f((unsigned short)d0[j]));
        acc[j + 8] += (bf2f((unsigned short)a1[j]) + bf2f((unsigned short)b1[j]))
                    + (bf2f((unsigned short)c1[j]) + bf2f((unsigned short)d1[j]));
      }
    }
    if (e + 2 <= e1) {
      int s0 = csr_src[e + 0];
      int s1 = csr_src[e + 1];
      const unsigned short* p0 = zb + (size_t)s0 * D + c;
      const unsigned short* p1 = zb + (size_t)s1 * D + c;
      bf16x8 a0 = *(const bf16x8*)(p0), a1 = *(const bf16x8*)(p0 + 8);
      bf16x8 b0 = *(const bf16x8*)(p1), b1 = *(const bf16x8*)(p1 + 8);
#pragma unroll
      for (int j = 0; j < 8; ++j) {
        acc[j]     += bf2f((unsigned short)a0[j]) + bf2f((unsigned short)b0[j]);
        acc[j + 8] += bf2f((unsigned short)a1[j]) + bf2f((unsigned short)b1[j]);
      }
      e += 2;
    }
    if (e < e1) {
      int s0 = csr_src[e];
      const unsigned short* p0 = zb + (size_t)s0 * D + c;
      bf16x8 a0 = *(const bf16x8*)(p0), a1 = *(const bf16x8*)(p0 + 8);
#pragma unroll
      for (int j = 0; j < 8; ++j) {
        acc[j]     += bf2f((unsigned short)a0[j]);
        acc[j + 8] += bf2f((unsigned short)a1[j]);
      }
    }
  } else {
    for (; e + 2 <= e1; e += 2) {
      int s0 = csr_src[e + 0];
      int s1 = csr_src[e + 1];
      const float* p0 = zf + (size_t)s0 * D + c;
      const float* p1 = zf + (size_t)s1 * D + c;
      float4 u0 = *(const float4*)(p0);
      float4 u1 = *(const float4*)(p0 + 4);
      float4 u2 = *(const float4*)(p0 + 8);
      float4 u3 = *(const float4*)(p0 + 12);
      float4 w0 = *(const float4*)(p1);
      float4 w1 = *(const float4*)(p1 + 4);
      float4 w2 = *(const float4*)(p1 + 8);
      float4 w3 = *(const float4*)(p1 + 12);
      acc[0]  += u0.x + w0.x; acc[1]  += u0.y + w0.y;
      acc[2]  += u0.z + w0.z; acc[3]  += u0.w + w0.w;
      acc[4]  += u1.x + w1.x; acc[5]  += u1.y + w1.y;
      acc[6]  += u1.z + w1.z; acc[7]  += u1.w + w1.w;
      acc[8]  += u2.x + w2.x; acc[9]  += u2.y + w2.y;
      acc[10] += u2.z + w2.z; acc[11] += u2.w + w2.w;
      acc[12] += u3.x + w3.x; acc[13] += u3.y + w3.y;
      acc[14] += u3.z + w3.z; acc[15] += u3.w + w3.w;
    }
    if (e < e1) {
      int s0 = csr_src[e];
      const float* p0 = zf + (size_t)s0 * D + c;
      float4 u0 = *(const float4*)(p0);
      float4 u1 = *(const float4*)(p0 + 4);
      float4 u2 = *(const float4*)(p0 + 8);
      float4 u3 = *(const float4*)(p0 + 12);
      acc[0]  += u0.x; acc[1]  += u0.y; acc[2]  += u0.z; acc[3]  += u0.w;
      acc[4]  += u1.x; acc[5]  += u1.y; acc[6]  += u1.z; acc[7]  += u1.w;
      acc[8]  += u2.x; acc[9]  += u2.y; acc[10] += u2.z; acc[11] += u2.w;
      acc[12] += u3.x; acc[13] += u3.y; acc[14] += u3.z; acc[15] += u3.w;
    }
  }

  bf16x8 o0, o1;
#pragma unroll
  for (int j = 0; j < 8; ++j) {
    o0[j] = (short)f2bf(acc[j]);
    o1[j] = (short)f2bf(acc[j + 8]);
  }
  unsigned short* q = agg + (size_t)node * D + c;
  *(bf16x8*)(q)     = o0;
  *(bf16x8*)(q + 8) = o1;
}

// ---------------- fused per-layer MLP: z = ReLU(ReLU(A@W1+b1)@W2+b2) -------
// R0 shape (128 rows/block, 32 rows/warp, 2-row fragments) + the R4 fix:
// ALL 32 B-fragments of each GEMM are hoisted into registers up front (one
// bf[8][4] array reused for W1 then W2, biases hoisted too). This collapses
// the 16 sequential ~300-cycle L2-latency rounds per warp (R3's measured
// stall: 90% idle, VGPR=56 proved no hoist) into 2. VGPR rises to ~200
// (8 waves/CU) -- R3 proved latency-chain depth dominates occupancy here.

template<bool LAST>
__global__ __launch_bounds__(256) void gemm_fused(const unsigned short* __restrict__ A,
    const unsigned short* __restrict__ Wt1, const float* __restrict__ b1v,
    const unsigned short* __restrict__ Wt2, const float* __restrict__ b2v,
    unsigned short* __restrict__ Zb, float* __restrict__ Zf, int M) {
  __shared__ unsigned short hs[4][32][136];
  int lane = threadIdx.x & 63;
  int wid  = threadIdx.x >> 6;
  int row_base = blockIdx.x * 128 + wid * 32;
  int c16 = lane & 15;
  int kq  = lane >> 4;
  int koff = kq * 8;

  bf16x8 a[2][4];
#pragma unroll
  for (int fr = 0; fr < 2; ++fr) {
    int row = row_base + fr * 16 + c16;
    row = row < M ? row : M - 1;
#pragma unroll
    for (int kk = 0; kk < 4; ++kk)
      a[fr][kk] = *(const bf16x8*)(A + (size_t)row * D + kk * 32 + koff);
  }

  // hoist all GEMM1 B-fragments + biases (32 x 16B = 128 VGPR)
  bf16x8 bf[8][4];
  float  bb[8];
#pragma unroll
  for (int fc = 0; fc < 8; ++fc) {
    bb[fc] = b1v[fc * 16 + c16];
#pragma unroll
    for (int kk = 0; kk < 4; ++kk)
      bf[fc][kk] = *(const bf16x8*)(Wt1 + (size_t)(fc * 16 + c16) * D + kk * 32 + koff);
  }

  // GEMM1 -> LDS
#pragma unroll
  for (int fc = 0; fc < 8; ++fc) {
    f32x4 acc0 = {0.f, 0.f, 0.f, 0.f};
    f32x4 acc1 = {0.f, 0.f, 0.f, 0.f};
    int col = fc * 16 + c16;
#pragma unroll
    for (int kk = 0; kk < 4; ++kk) {
      acc0 = __builtin_amdgcn_mfma_f32_16x16x32_bf16(a[0][kk], bf[fc][kk], acc0, 0, 0, 0);
      acc1 = __builtin_amdgcn_mfma_f32_16x16x32_bf16(a[1][kk], bf[fc][kk], acc1, 0, 0, 0);
    }
#pragma unroll
    for (int r = 0; r < 4; ++r) {
      int rl = kq * 4 + r;
      hs[wid][rl][col]      = f2bf(fmaxf(acc0[r] + bb[fc], 0.f));
      hs[wid][rl + 16][col] = f2bf(fmaxf(acc1[r] + bb[fc], 0.f));
    }
  }
  __syncthreads();

  bf16x8 a2[2][4];
#pragma unroll
  for (int fr = 0; fr < 2; ++fr)
#pragma unroll
    for (int kk = 0; kk < 4; ++kk)
      a2[fr][kk] = *(const bf16x8*)&hs[wid][fr * 16 + c16][kk * 32 + koff];

  // reload bf/bb with GEMM2 weights (register reuse; old values dead)
#pragma unroll
  for (int fc = 0; fc < 8; ++fc) {
    bb[fc] = b2v[fc * 16 + c16];
#pragma unroll
    for (int kk = 0; kk < 4; ++kk)
      bf[fc][kk] = *(const bf16x8*)(Wt2 + (size_t)(fc * 16 + c16) * D + kk * 32 + koff);
  }

  // GEMM2 -> global
#pragma unroll
  for (int fc = 0; fc < 8; ++fc) {
    f32x4 acc0 = {0.f, 0.f, 0.f, 0.f};
    f32x4 acc1 = {0.f, 0.f, 0.f, 0.f};
    int col = fc * 16 + c16;
#pragma unroll
    for (int kk = 0; kk < 4; ++kk) {
      acc0 = __builtin_amdgcn_mfma_f32_16x16x32_bf16(a2[0][kk], bf[fc][kk], acc0, 0, 0, 0);
      acc1 = __builtin_amdgcn_mfma_f32_16x16x32_bf16(a2[1][kk], bf[fc][kk], acc1, 0, 0, 0);
    }
#pragma unroll
    for (int r = 0; r < 4; ++r) {
      int row0 = row_base + kq * 4 + r;
      float v0 = fmaxf(acc0[r] + bb[fc], 0.f);
      if (row0 < M) {
        if constexpr (LAST) Zf[(size_t)row0 * D + col] = v0;
        else                Zb[(size_t)row0 * D + col] = f2bf(v0);
      }
      int row1 = row0 + 16;
      float v1 = fmaxf(acc1[r] + bb[fc], 0.f);
      if (row1 < M) {
        if constexpr (LAST) Zf[(size_t)row1 * D + col] = v1;
        else                Zb[(size_t)row1 * D + col] = f2bf(v1);
      }
    }
  }
}

// ---------------- pooling: sorted batch -> bounds + streaming mean ---------
// batch is sorted, so graph boundaries come from 128 binary searches; the
// mean kernel then streams contiguous rows with no data-dependent branches
// (the old serial batch[i] compare chain was ~128 dependent L2 loads/block).

__global__ __launch_bounds__(128) void pool_bounds(const int* __restrict__ batch,
                                                   int* __restrict__ start, int N) {
  int g = threadIdx.x;   // one block of 128
  int lo = 0, hi = N;
  while (lo < hi) {
    int mid = (lo + hi) >> 1;
    if (batch[mid] < g) lo = mid + 1; else hi = mid;
  }
  start[g] = lo;
  if (g == 0) start[NG] = N;
}

#define PCHUNKS 8
__global__ __launch_bounds__(128) void pool_mean(const float* __restrict__ z,
    const int* __restrict__ start, float* __restrict__ g) {
  int gid   = blockIdx.x >> 3;
  int chunk = blockIdx.x & (PCHUNKS - 1);
  int col = threadIdx.x;
  int s = start[gid], epos = start[gid + 1];
  int len = epos - s;
  if (len <= 0) return;
  int per = (len + PCHUNKS - 1) / PCHUNKS;
  int r0 = s + chunk * per;
  int r1 = min(r0 + per, epos);
  if (r0 >= r1) return;
  float a0 = 0.f, a1 = 0.f, a2 = 0.f, a3 = 0.f;
  int i = r0;
  for (; i + 4 <= r1; i += 4) {
    a0 += z[(size_t)(i + 0) * D + col];
    a1 += z[(size_t)(i + 1) * D + col];
    a2 += z[(size_t)(i + 2) * D + col];
    a3 += z[(size_t)(i + 3) * D + col];
  }
  for (; i < r1; ++i) a0 += z[(size_t)i * D + col];
  atomicAdd(g + (size_t)gid * D + col, (a0 + a1) + (a2 + a3));
}

__global__ void pool_div(float* __restrict__ g, const int* __restrict__ start) {
  int t = blockIdx.x * 256 + threadIdx.x;
  if (t >= NG * D) return;
  int gid = t >> 7;
  int cnt = start[gid + 1] - start[gid];
  g[t] = g[t] / fmaxf((float)cnt, 1.f);
}

extern "C" void kernel_launch(void* const* d_in, const int* in_sizes, int n_in,
                              void* d_out, int out_size, void* d_ws, size_t ws_size,
                              hipStream_t stream) {
  const float* x     = (const float*)d_in[0];
  const int*   ei    = (const int*)d_in[1];
  const int*   batch = (const int*)d_in[2];
  const float* W1    = (const float*)d_in[3];
  const float* b1    = (const float*)d_in[4];
  const float* W2    = (const float*)d_in[5];
  const float* b2    = (const float*)d_in[6];

  const int N = in_sizes[0] / D;       // 100000
  const int E = in_sizes[1] / 2;       // 640000
  const int* src = ei;
  const int* dst = ei + E;

  float* zout = (float*)d_out;
  float* g    = zout + (size_t)N * D;

  // workspace layout
  char* w = (char*)d_ws;
  unsigned short* agg     = (unsigned short*)w;    w += (size_t)N * D * 2;
  unsigned short* zb      = (unsigned short*)w;    w += (size_t)N * D * 2;
  unsigned short* Wt1     = (unsigned short*)w;    w += 3 * 16384 * 2;
  unsigned short* Wt2     = (unsigned short*)w;    w += 3 * 16384 * 2;
  int*            start   = (int*)w;               w += (NG + 4) * 4;
  int*            deg     = (int*)w;               w += (size_t)N * 4;
  int*            rowptr  = (int*)w;               w += (size_t)(N + 4) * 4;
  int*            pos     = (int*)w;               w += (size_t)N * 4;
  int*            bsum    = (int*)w;               w += 128 * 4;
  int*            csr_src = (int*)w;               w += (size_t)E * 4;

  const int nb = (N + 1023) / 1024;   // 98 <= 128

  // weight prep + deg/g zero (folded)
  int prep_threads = (3 * 128 * 128 > N) ? 3 * 128 * 128 : N;
  prep_w<<<(prep_threads + 255) / 256, 256, 0, stream>>>(W1, W2, Wt1, Wt2, deg, N, g);

  // graph boundaries (only needs batch; run early)
  pool_bounds<<<1, 128, 0, stream>>>(batch, start, N);

  // CSR build
  hist_deg<<<(E + 255) / 256, 256, 0, stream>>>(dst, deg, E);
  scan1<<<nb, 256, 0, stream>>>(deg, rowptr, bsum, N);
  scan2<<<1, 128, 0, stream>>>(bsum, nb);
  scan3<<<(N + 255) / 256, 256, 0, stream>>>(rowptr, pos, bsum, N, E);
  edge_scatter<<<(E + 255) / 256, 256, 0, stream>>>(src, dst, pos, csr_src, E);

  const int gather_blocks = (int)(((size_t)N * 8 + 255) / 256);   // 3125
  const int gemm_blocks   = (N + 127) / 128;                      // 782

  // layer 0 (input f32 x)
  gather_agg<false><<<gather_blocks, 256, 0, stream>>>(x, rowptr, csr_src, agg, N);
  gemm_fused<false><<<gemm_blocks, 256, 0, stream>>>(agg, Wt1, b1, Wt2, b2, zb, zout, N);
  // layer 1
  gather_agg<true><<<gather_blocks, 256, 0, stream>>>(zb, rowptr, csr_src, agg, N);
  gemm_fused<false><<<gemm_blocks, 256, 0, stream>>>(agg, Wt1 + 16384, b1 + 128,
                                                     Wt2 + 16384, b2 + 128, zb, zout, N);
  // layer 2 (writes f32 zout)
  gather_agg<true><<<gather_blocks, 256, 0, stream>>>(zb, rowptr, csr_src, agg, N);
  gemm_fused<true><<<gemm_blocks, 256, 0, stream>>>(agg, Wt1 + 32768, b1 + 256,
                                                    Wt2 + 32768, b2 + 256, zb, zout, N);

  pool_mean<<<NG * PCHUNKS, 128, 0, stream>>>(zout, start, g);
  pool_div<<<(NG * D + 255) / 256, 256, 0, stream>>>(g, start);
}